// Round 4
// baseline (1321.906 us; speedup 1.0000x reference)
//
#include <hip/hip_runtime.h>
#include <hip/hip_bf16.h>
#include <cstdint>
#include <cstddef>

#define B_ 2
#define N_ 2048
#define F_ 1024
#define H_ 16
#define D_ 64

typedef float f32x4 __attribute__((ext_vector_type(4)));
typedef short s16x8 __attribute__((ext_vector_type(8)));
typedef short s16x4 __attribute__((ext_vector_type(4)));

__device__ __forceinline__ unsigned short f2bf(float f) {
  union { __hip_bfloat16 h; unsigned short u; } c;
  c.h = __float2bfloat16(f);
  return c.u;
}
__device__ __forceinline__ float bf2f(unsigned short u) {
  union { __hip_bfloat16 h; unsigned short u; } c;
  c.u = u;
  return __bfloat162float(c.h);
}

// ---------------------------------------------------------------------
// fp32 -> bf16 bulk convert (8 elems/thread)
// ---------------------------------------------------------------------
__global__ __launch_bounds__(256) void cvt_bf16(const float* __restrict__ in,
                                                unsigned short* __restrict__ out,
                                                int n8) {
  const int t = blockIdx.x * 256 + threadIdx.x;
  if (t >= n8) return;
  const float4* p = (const float4*)in + (size_t)t * 2;
  float4 a = p[0], b = p[1];
  s16x8 o;
  o[0] = f2bf(a.x); o[1] = f2bf(a.y); o[2] = f2bf(a.z); o[3] = f2bf(a.w);
  o[4] = f2bf(b.x); o[5] = f2bf(b.y); o[6] = f2bf(b.z); o[7] = f2bf(b.w);
  *((s16x8*)out + t) = o;
}

// ---------------------------------------------------------------------
// w_qkv fp32 -> bf16 with ROW PERMUTATION: out row colp = c*1024 + h*64 + d
// corresponds to source row h*192 + d*3 + c. Makes GEMM output tiles
// class-uniform with d contiguous (shift/mask epilogue, coalesced stores).
// ---------------------------------------------------------------------
__global__ __launch_bounds__(256) void cvt_wqkv_perm(const float* __restrict__ in,
                                                     unsigned short* __restrict__ out) {
  const int t = blockIdx.x * 256 + threadIdx.x;   // 3072*128 tasks
  const int rowp = t >> 7;
  const int kk = (t & 127) * 8;
  const int c = rowp >> 10, rem = rowp & 1023;
  const int h = rem >> 6, d = rem & 63;
  const float* p = in + (size_t)(h * 192 + d * 3 + c) * 1024 + kk;
  float4 a = *(const float4*)p, b = *(const float4*)(p + 4);
  s16x8 o;
  o[0] = f2bf(a.x); o[1] = f2bf(a.y); o[2] = f2bf(a.z); o[3] = f2bf(a.w);
  o[4] = f2bf(b.x); o[5] = f2bf(b.y); o[6] = f2bf(b.z); o[7] = f2bf(b.w);
  *((s16x8*)&out[(size_t)rowp * 1024 + kk]) = o;
}

// ---------------------------------------------------------------------
// MFMA GEMM: C[M x Ncols] = A[M x 1024] * W[Ncols x 1024]^T, bf16 in.
// 128x128 tile, BK=64, 4 waves each 64x64 (4x4 frags of 16x16x32).
// MODE 0: qkv on PERMUTED W (colp = c*1024+h*64+d): class-specialized
//         epilogue -> Q bf16 / K bf16+kv fp32 / Vt bf16 packed + kv fp32
// MODE 1: out proj -> fp32 linear
// ---------------------------------------------------------------------
template <int MODE>
__global__ __launch_bounds__(256) void gemm_bf16(const unsigned short* __restrict__ A,
                                                 const unsigned short* __restrict__ W,
                                                 float* __restrict__ o0,
                                                 unsigned short* __restrict__ oQ,
                                                 unsigned short* __restrict__ oK,
                                                 unsigned short* __restrict__ oVt) {
  __shared__ unsigned short As[128 * 72];
  __shared__ unsigned short Bs[128 * 72];
  const int m0 = blockIdx.y * 128, c0 = blockIdx.x * 128;
  const int tid = threadIdx.x;
  const int wave = tid >> 6, lane = tid & 63;
  const int wm = (wave & 1) * 64, wn = (wave >> 1) * 64;
  const int lm = lane & 15, lq = lane >> 4;
  f32x4 acc[4][4] = {};
  for (int k0 = 0; k0 < 1024; k0 += 64) {
#pragma unroll
    for (int it = 0; it < 4; ++it) {
      const int chunk = it * 256 + tid;          // 0..1023
      const int row = chunk >> 3, kq = (chunk & 7) * 8;
      *(float4*)&As[row * 72 + kq] = *(const float4*)&A[(size_t)(m0 + row) * 1024 + k0 + kq];
      *(float4*)&Bs[row * 72 + kq] = *(const float4*)&W[(size_t)(c0 + row) * 1024 + k0 + kq];
    }
    __syncthreads();
#pragma unroll
    for (int ks = 0; ks < 2; ++ks) {
      s16x8 af[4], bfr[4];
#pragma unroll
      for (int i = 0; i < 4; ++i) {
        af[i] = *(const s16x8*)&As[(wm + i * 16 + lm) * 72 + ks * 32 + lq * 8];
        bfr[i] = *(const s16x8*)&Bs[(wn + i * 16 + lm) * 72 + ks * 32 + lq * 8];
      }
#pragma unroll
      for (int i = 0; i < 4; ++i)
#pragma unroll
        for (int j = 0; j < 4; ++j)
          acc[i][j] = __builtin_amdgcn_mfma_f32_16x16x32_bf16(af[i], bfr[j], acc[i][j], 0, 0, 0);
    }
    __syncthreads();
  }
  if (MODE == 1) {
#pragma unroll
    for (int i = 0; i < 4; ++i)
#pragma unroll
      for (int j = 0; j < 4; ++j)
#pragma unroll
        for (int r = 0; r < 4; ++r) {
          const int m = m0 + wm + i * 16 + lq * 4 + r;
          const int col = c0 + wn + j * 16 + lm;
          o0[(size_t)m * 1024 + col] = acc[i][j][r];
        }
  } else {
    const int cls = blockIdx.x >> 3;              // 0=q, 1=k, 2=v (uniform)
    const int colbase = (blockIdx.x & 7) * 128;
    if (cls == 0) {
#pragma unroll
      for (int i = 0; i < 4; ++i)
#pragma unroll
        for (int j = 0; j < 4; ++j) {
          const int cl = colbase + wn + j * 16 + lm;
          const int h = cl >> 6, d = cl & 63;
#pragma unroll
          for (int r = 0; r < 4; ++r) {
            const int m = m0 + wm + i * 16 + lq * 4 + r;
            const int bb = m >> 11, n = m & 2047;
            oQ[(((size_t)bb * H_ + h) * N_ + n) * D_ + d] = f2bf(acc[i][j][r]);
          }
        }
    } else if (cls == 1) {
#pragma unroll
      for (int i = 0; i < 4; ++i)
#pragma unroll
        for (int j = 0; j < 4; ++j) {
          const int cl = colbase + wn + j * 16 + lm;
          const int h = cl >> 6, d = cl & 63;
#pragma unroll
          for (int r = 0; r < 4; ++r) {
            const int m = m0 + wm + i * 16 + lq * 4 + r;
            const int bb = m >> 11, n = m & 2047;
            const size_t idx = (((size_t)bb * H_ + h) * N_ + n) * D_ + d;
            o0[idx] = acc[i][j][r];               // kv cache (k part)
            oK[idx] = f2bf(acc[i][j][r]);
          }
        }
    } else {
#pragma unroll
      for (int i = 0; i < 4; ++i) {
        const int n0 = m0 + wm + i * 16 + lq * 4;
        const int bb = n0 >> 11, nl = n0 & 2047;
#pragma unroll
        for (int j = 0; j < 4; ++j) {
          const int cl = colbase + wn + j * 16 + lm;
          const int h = cl >> 6, d = cl & 63;
          s16x4 vp;
#pragma unroll
          for (int r = 0; r < 4; ++r) {
            const size_t idx = (((size_t)bb * H_ + h) * N_ + nl + r) * D_ + d;
            o0[(size_t)B_ * H_ * N_ * D_ + idx] = acc[i][j][r];  // kv cache (v part)
            vp[r] = (short)f2bf(acc[i][j][r]);
          }
          *(s16x4*)&oVt[(((size_t)bb * H_ + h) * D_ + d) * N_ + nl] = vp;  // 8B packed
        }
      }
    }
  }
}

// ---------------------------------------------------------------------
// Scores: St[(i_loc*N + j)*16 + h] = Q[b,h,ic0+i,:] . K[b,h,j,:]
// h-innermost layout so mix's MFMA B-fragments load contiguously.
// ---------------------------------------------------------------------
__global__ __launch_bounds__(256) void gemm_scores(const unsigned short* __restrict__ Qb,
                                                   const unsigned short* __restrict__ Kb,
                                                   unsigned short* __restrict__ S,
                                                   int b, int ic0, int IC) {
  __shared__ unsigned short As[128 * 72];
  __shared__ unsigned short Bs[128 * 72];
  const int h = blockIdx.z, iT = blockIdx.y * 128, j0 = blockIdx.x * 128;
  const int tid = threadIdx.x;
  const int wave = tid >> 6, lane = tid & 63;
  const int wm = (wave & 1) * 64, wn = (wave >> 1) * 64;
  const int lm = lane & 15, lq = lane >> 4;
  const unsigned short* qp = Qb + (((size_t)b * H_ + h) * N_ + ic0 + iT) * D_;
  const unsigned short* kp = Kb + (((size_t)b * H_ + h) * N_ + j0) * D_;
#pragma unroll
  for (int it = 0; it < 4; ++it) {
    const int chunk = it * 256 + tid;
    const int row = chunk >> 3, kq = (chunk & 7) * 8;
    *(float4*)&As[row * 72 + kq] = *(const float4*)&qp[(size_t)row * 64 + kq];
    *(float4*)&Bs[row * 72 + kq] = *(const float4*)&kp[(size_t)row * 64 + kq];
  }
  __syncthreads();
  f32x4 acc[4][4] = {};
#pragma unroll
  for (int ks = 0; ks < 2; ++ks) {
    s16x8 af[4], bfr[4];
#pragma unroll
    for (int i = 0; i < 4; ++i) {
      af[i] = *(const s16x8*)&As[(wm + i * 16 + lm) * 72 + ks * 32 + lq * 8];
      bfr[i] = *(const s16x8*)&Bs[(wn + i * 16 + lm) * 72 + ks * 32 + lq * 8];
    }
#pragma unroll
    for (int i = 0; i < 4; ++i)
#pragma unroll
      for (int j = 0; j < 4; ++j)
        acc[i][j] = __builtin_amdgcn_mfma_f32_16x16x32_bf16(af[i], bfr[j], acc[i][j], 0, 0, 0);
  }
#pragma unroll
  for (int i = 0; i < 4; ++i)
#pragma unroll
    for (int j = 0; j < 4; ++j)
#pragma unroll
      for (int r = 0; r < 4; ++r) {
        const int ii = iT + wm + i * 16 + lq * 4 + r;
        const int jj = j0 + wn + j * 16 + lm;
        S[((size_t)ii * N_ + jj) * 16 + h] = f2bf(acc[i][j][r]);
      }
}

// ---------------------------------------------------------------------
// MFMA mix+softmax: one row i per block, 512 thr = 8 waves x 256 j.
// premix (A = wpre*0.125, K=16 heads zero-padded to 32) -> +bias -> exp
// -> per-g sum (quad shfl + LDS) -> postmix (A = wpost*inv_l) -> +bias.
// E kept in per-wave LDS tile [256 j][16 g] (B-layout for 2nd MFMA).
// ---------------------------------------------------------------------
__global__ __launch_bounds__(512) void mix_softmax3(const unsigned short* __restrict__ St,
                                                    unsigned short* __restrict__ P,
                                                    const float* __restrict__ wpre,
                                                    const float* __restrict__ bpre,
                                                    const float* __restrict__ wpost,
                                                    const float* __restrict__ bpost,
                                                    int IC) {
  __shared__ unsigned short Eld[8 * 256 * 16 + 32];
  __shared__ float lred[16][8];
  __shared__ float invl[16];
  const int i = blockIdx.x;
  const int tid = threadIdx.x;
  const int wave = tid >> 6, lane = tid & 63;
  const int lm = lane & 15, lq = lane >> 4;

  // A_pre: A[m=lm][k=lq*8+t] = wpre[lm][k]*0.125, zero for k>=16
  s16x8 apre;
#pragma unroll
  for (int t = 0; t < 8; ++t) apre[t] = 0;
  if (lq < 2) {
#pragma unroll
    for (int t = 0; t < 8; ++t)
      apre[t] = (short)f2bf(wpre[lm * 16 + lq * 8 + t] * 0.125f);
  }
  float bpre_r[4], bpost_r[4];
#pragma unroll
  for (int r = 0; r < 4; ++r) {
    bpre_r[r] = bpre[lq * 4 + r];
    bpost_r[r] = bpost[lq * 4 + r];
  }

  unsigned short* myE = &Eld[wave * 256 * 16];
  const unsigned short* sp = St + (size_t)i * (N_ * 16);
  float lpart[4] = {0.f, 0.f, 0.f, 0.f};
#pragma unroll
  for (int f = 0; f < 16; ++f) {
    const int j = wave * 256 + f * 16 + lm;
    s16x8 bfrag;
#pragma unroll
    for (int t = 0; t < 8; ++t) bfrag[t] = 0;
    if (lq < 2) bfrag = *(const s16x8*)&sp[(size_t)j * 16 + lq * 8];
    f32x4 c;
#pragma unroll
    for (int r = 0; r < 4; ++r) c[r] = 0.f;
    c = __builtin_amdgcn_mfma_f32_16x16x32_bf16(apre, bfrag, c, 0, 0, 0);
    s16x4 ep;
#pragma unroll
    for (int r = 0; r < 4; ++r) {
      const float e = __expf(c[r] + bpre_r[r]);   // row g = lq*4+r, col j
      lpart[r] += e;
      ep[r] = (short)f2bf(e);
    }
    *(s16x4*)&myE[(f * 16 + lm) * 16 + lq * 4] = ep;
  }
  // reduce lpart over j (16 lanes within quad)
#pragma unroll
  for (int m = 1; m < 16; m <<= 1)
#pragma unroll
    for (int r = 0; r < 4; ++r) lpart[r] += __shfl_xor(lpart[r], m);
  if (lm == 0) {
#pragma unroll
    for (int r = 0; r < 4; ++r) lred[lq * 4 + r][wave] = lpart[r];
  }
  __syncthreads();
  if (tid < 16) {
    float l = 0.f;
#pragma unroll
    for (int w = 0; w < 8; ++w) l += lred[tid][w];
    invl[tid] = __frcp_rn(l);
  }
  __syncthreads();

  // A_post: A[m=g'=lm][k=g=lq*8+t] = wpost[g'][g] * inv_l[g]
  s16x8 apost;
#pragma unroll
  for (int t = 0; t < 8; ++t) apost[t] = 0;
  if (lq < 2) {
#pragma unroll
    for (int t = 0; t < 8; ++t)
      apost[t] = (short)f2bf(wpost[lm * 16 + lq * 8 + t] * invl[lq * 8 + t]);
  }
#pragma unroll
  for (int f = 0; f < 16; ++f) {
    s16x8 bfrag = *(const s16x8*)&myE[(f * 16 + lm) * 16 + lq * 8];
    f32x4 c;
#pragma unroll
    for (int r = 0; r < 4; ++r) c[r] = 0.f;
    c = __builtin_amdgcn_mfma_f32_16x16x32_bf16(apost, bfrag, c, 0, 0, 0);
    const int j = wave * 256 + f * 16 + lm;
#pragma unroll
    for (int r = 0; r < 4; ++r)
      P[((size_t)(lq * 4 + r) * IC + i) * N_ + j] = f2bf(c[r] + bpost_r[r]);
  }
}

// ---------------------------------------------------------------------
// AV: O1[b, ic0+i, g*64+d] = sum_j P[g,i,j] * Vt[b,g,d,j], bf16 MFMA.
// 128(i) x 64(d) tile, BK=64. 4 waves, each 32x64 (2x4 frags).
// ---------------------------------------------------------------------
__global__ __launch_bounds__(256) void gemm_av(const unsigned short* __restrict__ P,
                                               const unsigned short* __restrict__ Vt,
                                               unsigned short* __restrict__ O1,
                                               int b, int ic0, int IC) {
  __shared__ unsigned short As[128 * 72];   // P tile [i][j]
  __shared__ unsigned short Bs[64 * 72];    // Vt tile [d][j]
  const int g = blockIdx.y, iT = blockIdx.x * 128;
  const int tid = threadIdx.x;
  const int wave = tid >> 6, lane = tid & 63;
  const int lm = lane & 15, lq = lane >> 4;
  const unsigned short* pp = P + ((size_t)g * IC + iT) * N_;
  const unsigned short* vp = Vt + (((size_t)b * H_ + g) * D_) * N_;
  f32x4 acc[2][4] = {};
  for (int k0 = 0; k0 < N_; k0 += 64) {
#pragma unroll
    for (int it = 0; it < 4; ++it) {
      const int chunk = it * 256 + tid;
      const int row = chunk >> 3, kq = (chunk & 7) * 8;
      *(float4*)&As[row * 72 + kq] = *(const float4*)&pp[(size_t)row * N_ + k0 + kq];
    }
#pragma unroll
    for (int it = 0; it < 2; ++it) {
      const int chunk = it * 256 + tid;
      const int row = chunk >> 3, kq = (chunk & 7) * 8;
      *(float4*)&Bs[row * 72 + kq] = *(const float4*)&vp[(size_t)row * N_ + k0 + kq];
    }
    __syncthreads();
#pragma unroll
    for (int ks = 0; ks < 2; ++ks) {
      s16x8 af[2], bfr[4];
#pragma unroll
      for (int i = 0; i < 2; ++i)
        af[i] = *(const s16x8*)&As[(wave * 32 + i * 16 + lm) * 72 + ks * 32 + lq * 8];
#pragma unroll
      for (int j = 0; j < 4; ++j)
        bfr[j] = *(const s16x8*)&Bs[(j * 16 + lm) * 72 + ks * 32 + lq * 8];
#pragma unroll
      for (int i = 0; i < 2; ++i)
#pragma unroll
        for (int j = 0; j < 4; ++j)
          acc[i][j] = __builtin_amdgcn_mfma_f32_16x16x32_bf16(af[i], bfr[j], acc[i][j], 0, 0, 0);
    }
    __syncthreads();
  }
#pragma unroll
  for (int i = 0; i < 2; ++i)
#pragma unroll
    for (int j = 0; j < 4; ++j)
#pragma unroll
      for (int r = 0; r < 4; ++r) {
        const int ii = iT + wave * 32 + i * 16 + lq * 4 + r;
        const int d = j * 16 + lm;
        O1[((size_t)b * N_ + ic0 + ii) * 1024 + (size_t)g * 64 + d] = f2bf(acc[i][j][r]);
      }
}

extern "C" void kernel_launch(void* const* d_in, const int* in_sizes, int n_in,
                              void* d_out, int out_size, void* d_ws,
                              size_t ws_size, hipStream_t stream) {
  (void)in_sizes; (void)n_in; (void)out_size;
  const float* x      = (const float*)d_in[0];
  const float* w_qkv  = (const float*)d_in[1];
  const float* w_out  = (const float*)d_in[2];
  const float* w_pre  = (const float*)d_in[3];
  const float* b_pre  = (const float*)d_in[4];
  const float* w_post = (const float*)d_in[5];
  const float* b_post = (const float*)d_in[6];

  float* out = (float*)d_out;                        // (B,N,F) fp32
  float* kv  = out + (size_t)B_ * N_ * F_;           // (2,B,H,N,D) fp32

  unsigned short* xb  = (unsigned short*)d_ws;       // 4096x1024
  unsigned short* wqb = xb + (size_t)4096 * 1024;    // 3072x1024 (permuted)
  unsigned short* wob = wqb + (size_t)3072 * 1024;   // 1024x1024
  unsigned short* Qb  = wob + (size_t)1024 * 1024;   // (B,H,N,D)
  unsigned short* Kb  = Qb + (size_t)B_ * H_ * N_ * D_;
  unsigned short* Vt  = Kb + (size_t)B_ * H_ * N_ * D_;   // (B,H,D,N)
  unsigned short* O1  = Vt + (size_t)B_ * H_ * N_ * D_;   // (B,N,1024)
  unsigned short* Sb  = O1 + (size_t)B_ * N_ * F_;        // (IC,N,16) h-innermost
  // Pb follows Sb, sized per chunk

  const size_t fixed_bytes = ((size_t)4096 * 1024 + (size_t)3072 * 1024 +
                              (size_t)1024 * 1024 + 4 * (size_t)B_ * H_ * N_ * D_) * 2;
  int IC = 2048;
  while (IC > 128 && fixed_bytes + 2 * (size_t)H_ * IC * N_ * 2 > ws_size) IC >>= 1;
  unsigned short* Pb = Sb + (size_t)H_ * IC * N_;

  cvt_bf16<<<dim3((4096 * 1024 / 8 + 255) / 256), 256, 0, stream>>>(x, xb, 4096 * 1024 / 8);
  cvt_wqkv_perm<<<dim3(3072 * 128 / 256), 256, 0, stream>>>(w_qkv, wqb);
  cvt_bf16<<<dim3((1024 * 1024 / 8 + 255) / 256), 256, 0, stream>>>(w_out, wob, 1024 * 1024 / 8);

  gemm_bf16<0><<<dim3(3072 / 128, 4096 / 128), 256, 0, stream>>>(xb, wqb, kv, Qb, Kb, Vt);

  for (int b = 0; b < B_; ++b) {
    for (int ic0 = 0; ic0 < N_; ic0 += IC) {
      gemm_scores<<<dim3(N_ / 128, IC / 128, H_), 256, 0, stream>>>(Qb, Kb, Sb, b, ic0, IC);
      mix_softmax3<<<dim3(IC), 512, 0, stream>>>(Sb, Pb, w_pre, b_pre, w_post, b_post, IC);
      gemm_av<<<dim3(IC / 128, H_), 256, 0, stream>>>(Pb, Vt, O1, b, ic0, IC);
    }
  }

  gemm_bf16<1><<<dim3(1024 / 128, 4096 / 128), 256, 0, stream>>>(O1, wob, out, nullptr, nullptr, nullptr);
}

// Round 5
// 458.549 us; speedup vs baseline: 2.8828x; 2.8828x over previous
//
#include <hip/hip_runtime.h>
#include <hip/hip_bf16.h>
#include <cstdint>
#include <cstddef>

#define B_ 2
#define N_ 2048
#define F_ 1024
#define H_ 16
#define D_ 64

typedef float f32x4 __attribute__((ext_vector_type(4)));
typedef short s16x8 __attribute__((ext_vector_type(8)));
typedef short s16x4 __attribute__((ext_vector_type(4)));

__device__ __forceinline__ unsigned short f2bf(float f) {
  union { __hip_bfloat16 h; unsigned short u; } c;
  c.h = __float2bfloat16(f);
  return c.u;
}
__device__ __forceinline__ float bf2f(unsigned short u) {
  union { __hip_bfloat16 h; unsigned short u; } c;
  c.u = u;
  return __bfloat162float(c.h);
}

// ---------------------------------------------------------------------
// fp32 -> bf16 bulk convert (8 elems/thread)
// ---------------------------------------------------------------------
__global__ __launch_bounds__(256) void cvt_bf16(const float* __restrict__ in,
                                                unsigned short* __restrict__ out,
                                                int n8) {
  const int t = blockIdx.x * 256 + threadIdx.x;
  if (t >= n8) return;
  const float4* p = (const float4*)in + (size_t)t * 2;
  float4 a = p[0], b = p[1];
  s16x8 o;
  o[0] = f2bf(a.x); o[1] = f2bf(a.y); o[2] = f2bf(a.z); o[3] = f2bf(a.w);
  o[4] = f2bf(b.x); o[5] = f2bf(b.y); o[6] = f2bf(b.z); o[7] = f2bf(b.w);
  *((s16x8*)out + t) = o;
}

// ---------------------------------------------------------------------
// w_qkv fp32 -> bf16 with row permutation: out row colp = c*1024 + h*64 + d
// ---------------------------------------------------------------------
__global__ __launch_bounds__(256) void cvt_wqkv_perm(const float* __restrict__ in,
                                                     unsigned short* __restrict__ out) {
  const int t = blockIdx.x * 256 + threadIdx.x;
  const int rowp = t >> 7;
  const int kk = (t & 127) * 8;
  const int c = rowp >> 10, rem = rowp & 1023;
  const int h = rem >> 6, d = rem & 63;
  const float* p = in + (size_t)(h * 192 + d * 3 + c) * 1024 + kk;
  float4 a = *(const float4*)p, b = *(const float4*)(p + 4);
  s16x8 o;
  o[0] = f2bf(a.x); o[1] = f2bf(a.y); o[2] = f2bf(a.z); o[3] = f2bf(a.w);
  o[4] = f2bf(b.x); o[5] = f2bf(b.y); o[6] = f2bf(b.z); o[7] = f2bf(b.w);
  *((s16x8*)&out[(size_t)rowp * 1024 + kk]) = o;
}

// ---------------------------------------------------------------------
// sum the two j-half fp32 O partials -> bf16 O1
// ---------------------------------------------------------------------
__global__ __launch_bounds__(256) void cvt_sum(const float* __restrict__ a,
                                               const float* __restrict__ b,
                                               unsigned short* __restrict__ out) {
  const int t = blockIdx.x * 256 + threadIdx.x;  // 1M threads, 4 elems each
  float4 x = *((const float4*)a + t);
  float4 y = *((const float4*)b + t);
  s16x4 o;
  o[0] = f2bf(x.x + y.x); o[1] = f2bf(x.y + y.y);
  o[2] = f2bf(x.z + y.z); o[3] = f2bf(x.w + y.w);
  *((s16x4*)out + t) = o;
}

// ---------------------------------------------------------------------
// MFMA GEMM (unchanged from round 4, which passed).
// ---------------------------------------------------------------------
template <int MODE>
__global__ __launch_bounds__(256) void gemm_bf16(const unsigned short* __restrict__ A,
                                                 const unsigned short* __restrict__ W,
                                                 float* __restrict__ o0,
                                                 unsigned short* __restrict__ oQ,
                                                 unsigned short* __restrict__ oK,
                                                 unsigned short* __restrict__ oVt) {
  __shared__ unsigned short As[128 * 72];
  __shared__ unsigned short Bs[128 * 72];
  const int m0 = blockIdx.y * 128, c0 = blockIdx.x * 128;
  const int tid = threadIdx.x;
  const int wave = tid >> 6, lane = tid & 63;
  const int wm = (wave & 1) * 64, wn = (wave >> 1) * 64;
  const int lm = lane & 15, lq = lane >> 4;
  f32x4 acc[4][4] = {};
  for (int k0 = 0; k0 < 1024; k0 += 64) {
#pragma unroll
    for (int it = 0; it < 4; ++it) {
      const int chunk = it * 256 + tid;
      const int row = chunk >> 3, kq = (chunk & 7) * 8;
      *(float4*)&As[row * 72 + kq] = *(const float4*)&A[(size_t)(m0 + row) * 1024 + k0 + kq];
      *(float4*)&Bs[row * 72 + kq] = *(const float4*)&W[(size_t)(c0 + row) * 1024 + k0 + kq];
    }
    __syncthreads();
#pragma unroll
    for (int ks = 0; ks < 2; ++ks) {
      s16x8 af[4], bfr[4];
#pragma unroll
      for (int i = 0; i < 4; ++i) {
        af[i] = *(const s16x8*)&As[(wm + i * 16 + lm) * 72 + ks * 32 + lq * 8];
        bfr[i] = *(const s16x8*)&Bs[(wn + i * 16 + lm) * 72 + ks * 32 + lq * 8];
      }
#pragma unroll
      for (int i = 0; i < 4; ++i)
#pragma unroll
        for (int j = 0; j < 4; ++j)
          acc[i][j] = __builtin_amdgcn_mfma_f32_16x16x32_bf16(af[i], bfr[j], acc[i][j], 0, 0, 0);
    }
    __syncthreads();
  }
  if (MODE == 1) {
#pragma unroll
    for (int i = 0; i < 4; ++i)
#pragma unroll
      for (int j = 0; j < 4; ++j)
#pragma unroll
        for (int r = 0; r < 4; ++r) {
          const int m = m0 + wm + i * 16 + lq * 4 + r;
          const int col = c0 + wn + j * 16 + lm;
          o0[(size_t)m * 1024 + col] = acc[i][j][r];
        }
  } else {
    const int cls = blockIdx.x >> 3;
    const int colbase = (blockIdx.x & 7) * 128;
    if (cls == 0) {
#pragma unroll
      for (int i = 0; i < 4; ++i)
#pragma unroll
        for (int j = 0; j < 4; ++j) {
          const int cl = colbase + wn + j * 16 + lm;
          const int h = cl >> 6, d = cl & 63;
#pragma unroll
          for (int r = 0; r < 4; ++r) {
            const int m = m0 + wm + i * 16 + lq * 4 + r;
            const int bb = m >> 11, n = m & 2047;
            oQ[(((size_t)bb * H_ + h) * N_ + n) * D_ + d] = f2bf(acc[i][j][r]);
          }
        }
    } else if (cls == 1) {
#pragma unroll
      for (int i = 0; i < 4; ++i)
#pragma unroll
        for (int j = 0; j < 4; ++j) {
          const int cl = colbase + wn + j * 16 + lm;
          const int h = cl >> 6, d = cl & 63;
#pragma unroll
          for (int r = 0; r < 4; ++r) {
            const int m = m0 + wm + i * 16 + lq * 4 + r;
            const int bb = m >> 11, n = m & 2047;
            const size_t idx = (((size_t)bb * H_ + h) * N_ + n) * D_ + d;
            o0[idx] = acc[i][j][r];
            oK[idx] = f2bf(acc[i][j][r]);
          }
        }
    } else {
#pragma unroll
      for (int i = 0; i < 4; ++i) {
        const int n0 = m0 + wm + i * 16 + lq * 4;
        const int bb = n0 >> 11, nl = n0 & 2047;
#pragma unroll
        for (int j = 0; j < 4; ++j) {
          const int cl = colbase + wn + j * 16 + lm;
          const int h = cl >> 6, d = cl & 63;
          s16x4 vp;
#pragma unroll
          for (int r = 0; r < 4; ++r) {
            const size_t idx = (((size_t)bb * H_ + h) * N_ + nl + r) * D_ + d;
            o0[(size_t)B_ * H_ * N_ * D_ + idx] = acc[i][j][r];
            vp[r] = (short)f2bf(acc[i][j][r]);
          }
          *(s16x4*)&oVt[(((size_t)bb * H_ + h) * D_ + d) * N_ + nl] = vp;
        }
      }
    }
  }
}

// =====================================================================
// Fused talking-heads attention, two passes.
// Block: (i-tile 32, j-half 1024, batch). 512 threads = 8 waves.
// Wave w owns heads {2w, 2w+1} for scores and AV; premix/postmix
// instances i_loc in {4w..4w+3} x jt in {0,1}.
// Fragment conventions (HW-validated rounds 2-4):
//   A: lane m=lm, k=lq*8+t ; B: lane n=lm, k=lq*8+t ; C: col=lm, row=lq*4+r
// LDS strides padded for bank-conflict-freedom: h/g-stride 20, i-stride 648,
// Psh: j-stride 36, g-stride 1160.
// =====================================================================
#define SS_I 648
#define SS_J 20
#define PS_G 1160
#define PS_I 36

// -------------------- pass 1: row sums l --------------------
__global__ __launch_bounds__(512) void attn_l(const unsigned short* __restrict__ Qb,
                                              const unsigned short* __restrict__ Kb,
                                              const float* __restrict__ wpre,
                                              const float* __restrict__ bpre,
                                              float* __restrict__ l_glob) {
  __shared__ unsigned short Ssh[32 * SS_I];
  const int tid = threadIdx.x;
  const int wave = tid >> 6, lane = tid & 63;
  const int lm = lane & 15, lq = lane >> 4;
  const int b = blockIdx.z, jh = blockIdx.y;
  const int i0 = blockIdx.x * 32;
  const int j00 = jh * 1024;
  const int h0 = wave * 2;

  s16x8 aq[2][2][2];
#pragma unroll
  for (int hh = 0; hh < 2; ++hh)
#pragma unroll
    for (int mi = 0; mi < 2; ++mi)
#pragma unroll
      for (int ks = 0; ks < 2; ++ks)
        aq[hh][mi][ks] = *(const s16x8*)&Qb[(((size_t)(b * H_ + h0 + hh) * N_) + i0 + mi * 16 + lm) * D_ + ks * 32 + lq * 8];

  s16x8 apre;
#pragma unroll
  for (int t = 0; t < 8; ++t) apre[t] = 0;
  if (lq < 2)
#pragma unroll
    for (int t = 0; t < 8; ++t) apre[t] = (short)f2bf(wpre[lm * 16 + lq * 8 + t] * 0.125f);
  float bpre_r[4];
#pragma unroll
  for (int r = 0; r < 4; ++r) bpre_r[r] = bpre[lq * 4 + r];

  float lacc[4][4] = {};

  for (int js = 0; js < 1024; js += 32) {
    const int j0 = j00 + js;
    s16x8 bk[2][2][2];
#pragma unroll
    for (int hh = 0; hh < 2; ++hh)
#pragma unroll
      for (int jt = 0; jt < 2; ++jt)
#pragma unroll
        for (int ks = 0; ks < 2; ++ks)
          bk[hh][jt][ks] = *(const s16x8*)&Kb[(((size_t)(b * H_ + h0 + hh) * N_) + j0 + jt * 16 + lm) * D_ + ks * 32 + lq * 8];
    f32x4 cs[2][2][2];
#pragma unroll
    for (int hh = 0; hh < 2; ++hh)
#pragma unroll
      for (int mi = 0; mi < 2; ++mi)
#pragma unroll
        for (int jt = 0; jt < 2; ++jt) {
          f32x4 c = {};
          c = __builtin_amdgcn_mfma_f32_16x16x32_bf16(aq[hh][mi][0], bk[hh][jt][0], c, 0, 0, 0);
          c = __builtin_amdgcn_mfma_f32_16x16x32_bf16(aq[hh][mi][1], bk[hh][jt][1], c, 0, 0, 0);
          cs[hh][mi][jt] = c;
        }
    __syncthreads();
#pragma unroll
    for (int hh = 0; hh < 2; ++hh)
#pragma unroll
      for (int mi = 0; mi < 2; ++mi)
#pragma unroll
        for (int jt = 0; jt < 2; ++jt)
#pragma unroll
          for (int r = 0; r < 4; ++r)
            Ssh[(mi * 16 + lq * 4 + r) * SS_I + (jt * 16 + lm) * SS_J + h0 + hh] = f2bf(cs[hh][mi][jt][r]);
    __syncthreads();
#pragma unroll
    for (int ii = 0; ii < 4; ++ii) {
      const int i_loc = wave * 4 + ii;
#pragma unroll
      for (int jt = 0; jt < 2; ++jt) {
        s16x8 bs;
#pragma unroll
        for (int t = 0; t < 8; ++t) bs[t] = 0;
        if (lq < 2) {
          s16x4 p0 = *(const s16x4*)&Ssh[i_loc * SS_I + (jt * 16 + lm) * SS_J + lq * 8];
          s16x4 p1 = *(const s16x4*)&Ssh[i_loc * SS_I + (jt * 16 + lm) * SS_J + lq * 8 + 4];
          bs[0] = p0[0]; bs[1] = p0[1]; bs[2] = p0[2]; bs[3] = p0[3];
          bs[4] = p1[0]; bs[5] = p1[1]; bs[6] = p1[2]; bs[7] = p1[3];
        }
        f32x4 c = {};
        c = __builtin_amdgcn_mfma_f32_16x16x32_bf16(apre, bs, c, 0, 0, 0);
#pragma unroll
        for (int r = 0; r < 4; ++r) lacc[ii][r] += __expf(c[r] + bpre_r[r]);
      }
    }
  }
#pragma unroll
  for (int ii = 0; ii < 4; ++ii)
#pragma unroll
    for (int r = 0; r < 4; ++r) {
      float v = lacc[ii][r];
      v += __shfl_xor(v, 1); v += __shfl_xor(v, 2);
      v += __shfl_xor(v, 4); v += __shfl_xor(v, 8);
      if (lm == 0)
        atomicAdd(&l_glob[((size_t)b * N_ + i0 + wave * 4 + ii) * H_ + lq * 4 + r], v);
    }
}

// -------------------- pass 2: full pipeline + AV --------------------
__global__ __launch_bounds__(512) void attn_av(const unsigned short* __restrict__ Qb,
                                               const unsigned short* __restrict__ Kb,
                                               const unsigned short* __restrict__ Vt,
                                               const float* __restrict__ wpre,
                                               const float* __restrict__ bpre,
                                               const float* __restrict__ wpost,
                                               const float* __restrict__ bpost,
                                               const float* __restrict__ l_glob,
                                               float* __restrict__ Opart) {
  __shared__ unsigned short Ssh[32 * SS_I];
  __shared__ unsigned short Esh[32 * SS_I];
  __shared__ unsigned short Psh[16 * PS_G];
  __shared__ float linv[32 * 16];
  const int tid = threadIdx.x;
  const int wave = tid >> 6, lane = tid & 63;
  const int lm = lane & 15, lq = lane >> 4;
  const int b = blockIdx.z, jh = blockIdx.y;
  const int i0 = blockIdx.x * 32;
  const int j00 = jh * 1024;
  const int h0 = wave * 2;
  float* Oout = Opart + (size_t)jh * B_ * N_ * 1024;

  {
    const int il = tid >> 4, g = tid & 15;
    linv[tid] = 1.0f / l_glob[((size_t)b * N_ + i0 + il) * H_ + g];
  }

  s16x8 aq[2][2][2];
#pragma unroll
  for (int hh = 0; hh < 2; ++hh)
#pragma unroll
    for (int mi = 0; mi < 2; ++mi)
#pragma unroll
      for (int ks = 0; ks < 2; ++ks)
        aq[hh][mi][ks] = *(const s16x8*)&Qb[(((size_t)(b * H_ + h0 + hh) * N_) + i0 + mi * 16 + lm) * D_ + ks * 32 + lq * 8];

  s16x8 apre, apost;
#pragma unroll
  for (int t = 0; t < 8; ++t) { apre[t] = 0; apost[t] = 0; }
  if (lq < 2)
#pragma unroll
    for (int t = 0; t < 8; ++t) {
      apre[t] = (short)f2bf(wpre[lm * 16 + lq * 8 + t] * 0.125f);
      apost[t] = (short)f2bf(wpost[lm * 16 + lq * 8 + t]);
    }
  float bpre_r[4], bpost_r[4];
#pragma unroll
  for (int r = 0; r < 4; ++r) {
    bpre_r[r] = bpre[lq * 4 + r];
    bpost_r[r] = bpost[lq * 4 + r];
  }

  f32x4 acc[2][2][4] = {};  // [g][mi][nd]
  __syncthreads();          // linv visible

  for (int js = 0; js < 1024; js += 32) {
    const int j0 = j00 + js;
    s16x8 bk[2][2][2];
#pragma unroll
    for (int hh = 0; hh < 2; ++hh)
#pragma unroll
      for (int jt = 0; jt < 2; ++jt)
#pragma unroll
        for (int ks = 0; ks < 2; ++ks)
          bk[hh][jt][ks] = *(const s16x8*)&Kb[(((size_t)(b * H_ + h0 + hh) * N_) + j0 + jt * 16 + lm) * D_ + ks * 32 + lq * 8];
    s16x8 bv[2][4];
#pragma unroll
    for (int g = 0; g < 2; ++g)
#pragma unroll
      for (int nd = 0; nd < 4; ++nd)
        bv[g][nd] = *(const s16x8*)&Vt[(((size_t)(b * H_ + h0 + g) * D_) + nd * 16 + lm) * N_ + j0 + lq * 8];

    f32x4 cs[2][2][2];
#pragma unroll
    for (int hh = 0; hh < 2; ++hh)
#pragma unroll
      for (int mi = 0; mi < 2; ++mi)
#pragma unroll
        for (int jt = 0; jt < 2; ++jt) {
          f32x4 c = {};
          c = __builtin_amdgcn_mfma_f32_16x16x32_bf16(aq[hh][mi][0], bk[hh][jt][0], c, 0, 0, 0);
          c = __builtin_amdgcn_mfma_f32_16x16x32_bf16(aq[hh][mi][1], bk[hh][jt][1], c, 0, 0, 0);
          cs[hh][mi][jt] = c;
        }
    __syncthreads();  // B_a: prior premix/AV reads done
#pragma unroll
    for (int hh = 0; hh < 2; ++hh)
#pragma unroll
      for (int mi = 0; mi < 2; ++mi)
#pragma unroll
        for (int jt = 0; jt < 2; ++jt)
#pragma unroll
          for (int r = 0; r < 4; ++r)
            Ssh[(mi * 16 + lq * 4 + r) * SS_I + (jt * 16 + lm) * SS_J + h0 + hh] = f2bf(cs[hh][mi][jt][r]);
    __syncthreads();  // B_b
#pragma unroll
    for (int ii = 0; ii < 4; ++ii) {
      const int i_loc = wave * 4 + ii;
      const float4 li = *(const float4*)&linv[i_loc * 16 + lq * 4];
#pragma unroll
      for (int jt = 0; jt < 2; ++jt) {
        s16x8 bs;
#pragma unroll
        for (int t = 0; t < 8; ++t) bs[t] = 0;
        if (lq < 2) {
          s16x4 p0 = *(const s16x4*)&Ssh[i_loc * SS_I + (jt * 16 + lm) * SS_J + lq * 8];
          s16x4 p1 = *(const s16x4*)&Ssh[i_loc * SS_I + (jt * 16 + lm) * SS_J + lq * 8 + 4];
          bs[0] = p0[0]; bs[1] = p0[1]; bs[2] = p0[2]; bs[3] = p0[3];
          bs[4] = p1[0]; bs[5] = p1[1]; bs[6] = p1[2]; bs[7] = p1[3];
        }
        f32x4 c = {};
        c = __builtin_amdgcn_mfma_f32_16x16x32_bf16(apre, bs, c, 0, 0, 0);
        s16x4 ep;
        const float lif[4] = {li.x, li.y, li.z, li.w};
#pragma unroll
        for (int r = 0; r < 4; ++r)
          ep[r] = (short)f2bf(__expf(c[r] + bpre_r[r]) * lif[r]);
        *(s16x4*)&Esh[i_loc * SS_I + (jt * 16 + lm) * SS_J + lq * 4] = ep;
      }
    }
    __syncthreads();  // B_c
#pragma unroll
    for (int ii = 0; ii < 4; ++ii) {
      const int i_loc = wave * 4 + ii;
#pragma unroll
      for (int jt = 0; jt < 2; ++jt) {
        s16x8 be;
#pragma unroll
        for (int t = 0; t < 8; ++t) be[t] = 0;
        if (lq < 2) {
          s16x4 p0 = *(const s16x4*)&Esh[i_loc * SS_I + (jt * 16 + lm) * SS_J + lq * 8];
          s16x4 p1 = *(const s16x4*)&Esh[i_loc * SS_I + (jt * 16 + lm) * SS_J + lq * 8 + 4];
          be[0] = p0[0]; be[1] = p0[1]; be[2] = p0[2]; be[3] = p0[3];
          be[4] = p1[0]; be[5] = p1[1]; be[6] = p1[2]; be[7] = p1[3];
        }
        f32x4 c2 = {};
        c2 = __builtin_amdgcn_mfma_f32_16x16x32_bf16(apost, be, c2, 0, 0, 0);
#pragma unroll
        for (int r = 0; r < 4; ++r)
          Psh[(lq * 4 + r) * PS_G + i_loc * PS_I + jt * 16 + lm] = f2bf(c2[r] + bpost_r[r]);
      }
    }
    __syncthreads();  // B_d
#pragma unroll
    for (int g = 0; g < 2; ++g) {
      const int gg = wave * 2 + g;
#pragma unroll
      for (int mi = 0; mi < 2; ++mi) {
        s16x4 a0 = *(const s16x4*)&Psh[gg * PS_G + (mi * 16 + lm) * PS_I + lq * 8];
        s16x4 a1 = *(const s16x4*)&Psh[gg * PS_G + (mi * 16 + lm) * PS_I + lq * 8 + 4];
        s16x8 ap;
        ap[0] = a0[0]; ap[1] = a0[1]; ap[2] = a0[2]; ap[3] = a0[3];
        ap[4] = a1[0]; ap[5] = a1[1]; ap[6] = a1[2]; ap[7] = a1[3];
#pragma unroll
        for (int nd = 0; nd < 4; ++nd)
          acc[g][mi][nd] = __builtin_amdgcn_mfma_f32_16x16x32_bf16(ap, bv[g][nd], acc[g][mi][nd], 0, 0, 0);
      }
    }
  }
#pragma unroll
  for (int g = 0; g < 2; ++g)
#pragma unroll
    for (int mi = 0; mi < 2; ++mi)
#pragma unroll
      for (int nd = 0; nd < 4; ++nd)
#pragma unroll
        for (int r = 0; r < 4; ++r)
          Oout[((size_t)b * N_ + i0 + mi * 16 + lq * 4 + r) * 1024 + (wave * 2 + g) * 64 + nd * 16 + lm] = acc[g][mi][nd][r];
}

extern "C" void kernel_launch(void* const* d_in, const int* in_sizes, int n_in,
                              void* d_out, int out_size, void* d_ws,
                              size_t ws_size, hipStream_t stream) {
  (void)in_sizes; (void)n_in; (void)out_size; (void)ws_size;
  const float* x      = (const float*)d_in[0];
  const float* w_qkv  = (const float*)d_in[1];
  const float* w_out  = (const float*)d_in[2];
  const float* w_pre  = (const float*)d_in[3];
  const float* b_pre  = (const float*)d_in[4];
  const float* w_post = (const float*)d_in[5];
  const float* b_post = (const float*)d_in[6];

  float* out = (float*)d_out;                        // (B,N,F) fp32
  float* kv  = out + (size_t)B_ * N_ * F_;           // (2,B,H,N,D) fp32

  unsigned short* xb  = (unsigned short*)d_ws;            // 4096x1024
  unsigned short* wqb = xb + (size_t)4096 * 1024;         // 3072x1024 (permuted)
  unsigned short* wob = wqb + (size_t)3072 * 1024;        // 1024x1024
  unsigned short* Qb  = wob + (size_t)1024 * 1024;        // (B,H,N,D)
  unsigned short* Kb  = Qb + (size_t)B_ * H_ * N_ * D_;
  unsigned short* Vt  = Kb + (size_t)B_ * H_ * N_ * D_;   // (B,H,D,N)
  unsigned short* O1  = Vt + (size_t)B_ * H_ * N_ * D_;   // (B,N,1024) bf16
  float* l_glob = (float*)(O1 + (size_t)B_ * N_ * F_);    // (B,N,16) fp32
  float* Oh0 = l_glob + (size_t)B_ * N_ * H_;             // (B,N,1024) fp32
  float* Oh1 = Oh0 + (size_t)B_ * N_ * F_;                // (B,N,1024) fp32

  cvt_bf16<<<dim3(4096 * 1024 / 8 / 256), 256, 0, stream>>>(x, xb, 4096 * 1024 / 8);
  cvt_wqkv_perm<<<dim3(3072 * 128 / 256), 256, 0, stream>>>(w_qkv, wqb);
  cvt_bf16<<<dim3(1024 * 1024 / 8 / 256), 256, 0, stream>>>(w_out, wob, 1024 * 1024 / 8);
  hipMemsetAsync(l_glob, 0, (size_t)B_ * N_ * H_ * 4, stream);

  gemm_bf16<0><<<dim3(3072 / 128, 4096 / 128), 256, 0, stream>>>(xb, wqb, kv, Qb, Kb, Vt);

  attn_l<<<dim3(N_ / 32, 2, B_), 512, 0, stream>>>(Qb, Kb, w_pre, b_pre, l_glob);
  attn_av<<<dim3(N_ / 32, 2, B_), 512, 0, stream>>>(Qb, Kb, Vt, w_pre, b_pre, w_post, b_post,
                                                    l_glob, Oh0);

  cvt_sum<<<dim3(B_ * N_ * F_ / 4 / 256), 256, 0, stream>>>(Oh0, Oh1, O1);

  gemm_bf16<1><<<dim3(1024 / 128, 4096 / 128), 256, 0, stream>>>(O1, wob, out, nullptr, nullptr, nullptr);
}